// Round 15
// baseline (122.733 us; speedup 1.0000x reference)
//
#include <hip/hip_runtime.h>
#include <hip/hip_bf16.h>
#include <stdint.h>

#define B_ROWS 4096
#define D_DIM  512
#define N2     8192
#define NBLK   64          // 8192 / 128
#define NTRI   (NBLK * (NBLK + 1) / 2)   // 2080 upper-tri blocks (2080 % 8 == 0)
#define BK     64          // fp8: 128x64 panel = 8 KB

typedef __attribute__((ext_vector_type(4))) float f32x4;

// ---------------------------------------------------------------------------
// Kernel 1 (R15): wave-per-row normalize + fp8 cast. 2048 blocks x 256 thr;
// each wave owns one row: 64 lanes x 8 floats (2x float4), shfl-only reduce,
// 8B uint2 fp8 store. Zeroes denom.
// ---------------------------------------------------------------------------
__global__ __launch_bounds__(256) void normalize_kernel(const float* __restrict__ zi,
                                                        const float* __restrict__ zj,
                                                        uint2* __restrict__ zn8,
                                                        float* __restrict__ denom) {
    const int t    = threadIdx.x;
    const int lane = t & 63;
    const int row  = blockIdx.x * 4 + (t >> 6);
    if (lane == 0) denom[row] = 0.0f;

    const float* src = (row < B_ROWS) ? (zi + (size_t)row * D_DIM)
                                      : (zj + (size_t)(row - B_ROWS) * D_DIM);
    const float4 a = ((const float4*)src)[lane * 2 + 0];
    const float4 b = ((const float4*)src)[lane * 2 + 1];
    float ss = a.x*a.x + a.y*a.y + a.z*a.z + a.w*a.w
             + b.x*b.x + b.y*b.y + b.z*b.z + b.w*b.w;
    #pragma unroll
    for (int off = 1; off < 64; off <<= 1) ss += __shfl_xor(ss, off);
    const float inv = 1.0f / sqrtf(ss);   // norms ~22.6 >> eps

    int w0 = __builtin_amdgcn_cvt_pk_fp8_f32(a.x * inv, a.y * inv, 0, false);
    w0     = __builtin_amdgcn_cvt_pk_fp8_f32(a.z * inv, a.w * inv, w0, true);
    int w1 = __builtin_amdgcn_cvt_pk_fp8_f32(b.x * inv, b.y * inv, 0, false);
    w1     = __builtin_amdgcn_cvt_pk_fp8_f32(b.z * inv, b.w * inv, w1, true);
    uint2 h; h.x = (unsigned)w0; h.y = (unsigned)w1;
    zn8[(size_t)row * (D_DIM / 8) + lane] = h;
}

// ---------------------------------------------------------------------------
// Kernel 2 (R15): R14 fp8+swizzle gram + occupancy-neutral double-buffer.
// 2x(8+8) KB = 32 KB LDS -> still 5 blocks/CU (VGPR-capped at 88 anyway).
// Per K-step: stage kt+1 into buf^1, compute kt from buf, ONE syncthreads
// (its compiler vmcnt(0) drain lands the overlapped prefetch). T3-min-2phase.
// ---------------------------------------------------------------------------
__global__ __launch_bounds__(256) void gram_kernel(const uchar* __restrict__ zn8,
                                                   float* __restrict__ denom,
                                                   float* __restrict__ pos) {
    __shared__ uchar As[2][128 * BK];   // 2 x 8 KB
    __shared__ uchar Bs[2][128 * BK];   // 2 x 8 KB

    const int t    = threadIdx.x;
    const int lane = t & 63;
    const int wave = t >> 6;
    const int wr   = wave >> 1;       // wave-row quadrant (0..1)
    const int wc   = wave & 1;        // wave-col quadrant (0..1)

    // T1: XCD-chunked bijective swizzle (2080 = 8 * 260), then tri-decode
    const int g   = blockIdx.x;
    const int bid = (g & 7) * (NTRI / 8) + (g >> 3);
    int by = (int)((sqrtf(8.0f * (float)bid + 1.0f) - 1.0f) * 0.5f);
    while ((by * (by + 1)) / 2 > bid) --by;
    while (((by + 1) * (by + 2)) / 2 <= bid) ++by;
    const int bx = bid - (by * (by + 1)) / 2;
    const int row0 = bx * 128;
    const int col0 = by * 128;
    const bool offdiag = (bx != by);

    // staging (R14-validated): dest linear (t*16 +half*4096), source chunk
    // pre-swizzled: (t&3) ^ g(row), g(row)=(row>>1)&3=(t>>3)&3
    const int srow = t >> 2;                                   // 0..63
    const int scol = (((t & 3) ^ ((t >> 3) & 3)) * 16);        // swizzled src bytes

    f32x4 acc[4][4];
    #pragma unroll
    for (int m = 0; m < 4; ++m)
        #pragma unroll
        for (int n = 0; n < 4; ++n)
            acc[m][n] = (f32x4){0.f, 0.f, 0.f, 0.f};

    const int lrow_a = wr * 64 + (lane & 15);
    const int lrow_b = wc * 64 + (lane & 15);
    const int hi     = lane >> 4;                 // 0..3
    const int g4     = ((lane & 15) >> 1) & 3;    // g(row) for this lane's rows

    #define STAGE(buf, kt)                                                           \
        do {                                                                         \
            const int k0_ = (kt) * BK;                                               \
            _Pragma("unroll")                                                        \
            for (int half = 0; half < 2; ++half) {                                   \
                const int r_ = srow + half * 64;                                     \
                const uchar* gA_ = zn8 + (size_t)(row0 + r_) * D_DIM + k0_ + scol;   \
                const uchar* gB_ = zn8 + (size_t)(col0 + r_) * D_DIM + k0_ + scol;   \
                __builtin_amdgcn_global_load_lds(                                    \
                    (const __attribute__((address_space(1))) void*)gA_,              \
                    (__attribute__((address_space(3))) void*)(As[(buf)] + (size_t)(t + half * 256) * 16), \
                    16, 0, 0);                                                       \
                __builtin_amdgcn_global_load_lds(                                    \
                    (const __attribute__((address_space(1))) void*)gB_,              \
                    (__attribute__((address_space(3))) void*)(Bs[(buf)] + (size_t)(t + half * 256) * 16), \
                    16, 0, 0);                                                       \
            }                                                                        \
        } while (0)

    STAGE(0, 0);
    __syncthreads();                   // drain prologue stage
    int cur = 0;
    for (int kt = 0; kt < D_DIM / BK; ++kt) {
        if (kt + 1 < D_DIM / BK) STAGE(cur ^ 1, kt + 1);   // prefetch overlaps compute

        #pragma unroll
        for (int s = 0; s < 2; ++s) {
            const int ca = (((2 * s + (hi >> 1)) ^ g4) * 16) + (hi & 1) * 8;
            long long af[4], bfr[4];
            #pragma unroll
            for (int m = 0; m < 4; ++m)
                af[m] = *(const long long*)(As[cur] + (size_t)(lrow_a + m * 16) * BK + ca);
            #pragma unroll
            for (int n = 0; n < 4; ++n)
                bfr[n] = *(const long long*)(Bs[cur] + (size_t)(lrow_b + n * 16) * BK + ca);

            #pragma unroll
            for (int m = 0; m < 4; ++m)
                #pragma unroll
                for (int n = 0; n < 4; ++n)
                    acc[m][n] = __builtin_amdgcn_mfma_f32_16x16x32_fp8_fp8(af[m], bfr[n], acc[m][n], 0, 0, 0);
        }
        __syncthreads();   // vmcnt(0)+lgkmcnt(0): prefetch landed, reads done
        cur ^= 1;
    }
    #undef STAGE

    // Epilogue: e = exp(2s) (diag masked); positives at gcol-grow==B;
    // row sums into denom[row]; col sums into denom[col] for off-diag blocks.
    const int colbase = col0 + wc * 64 + (lane & 15);
    float cs[4] = {0.f, 0.f, 0.f, 0.f};
    #pragma unroll
    for (int m = 0; m < 4; ++m) {
        const int rowbase = row0 + wr * 64 + m * 16 + (lane >> 4) * 4;
        float rs[4] = {0.f, 0.f, 0.f, 0.f};
        #pragma unroll
        for (int n = 0; n < 4; ++n) {
            const int gcol = colbase + n * 16;
            #pragma unroll
            for (int j = 0; j < 4; ++j) {
                const int grow = rowbase + j;
                const float s2 = 2.0f * acc[m][n][j];   // sim / T,  T = 0.5
                const float e  = (grow == gcol) ? 0.0f : __expf(s2);
                if (gcol - grow == B_ROWS) {            // +B diagonal (once per pair)
                    pos[grow] = s2;
                    pos[gcol] = s2;
                }
                rs[j] += e;
                cs[n] += e;
            }
        }
        #pragma unroll
        for (int off = 1; off < 16; off <<= 1) {
            rs[0] += __shfl_xor(rs[0], off);
            rs[1] += __shfl_xor(rs[1], off);
            rs[2] += __shfl_xor(rs[2], off);
            rs[3] += __shfl_xor(rs[3], off);
        }
        if ((lane & 15) == 0) {
            atomicAdd(&denom[rowbase + 0], rs[0]);
            atomicAdd(&denom[rowbase + 1], rs[1]);
            atomicAdd(&denom[rowbase + 2], rs[2]);
            atomicAdd(&denom[rowbase + 3], rs[3]);
        }
    }
    if (offdiag) {
        #pragma unroll
        for (int off = 16; off < 64; off <<= 1) {
            cs[0] += __shfl_xor(cs[0], off);
            cs[1] += __shfl_xor(cs[1], off);
            cs[2] += __shfl_xor(cs[2], off);
            cs[3] += __shfl_xor(cs[3], off);
        }
        if (lane < 16) {
            atomicAdd(&denom[colbase + 0],  cs[0]);
            atomicAdd(&denom[colbase + 16], cs[1]);
            atomicAdd(&denom[colbase + 32], cs[2]);
            atomicAdd(&denom[colbase + 48], cs[3]);
        }
    }
}

// ---------------------------------------------------------------------------
// Kernel 3: loss = mean( log(denom + 1e-8) - pos )
// ---------------------------------------------------------------------------
__global__ void loss_kernel(const float* __restrict__ denom,
                            const float* __restrict__ pos,
                            float* __restrict__ out) {
    const int t = threadIdx.x;      // 1024 threads
    float partial = 0.f;
    for (int i = t; i < N2; i += 1024)
        partial += logf(denom[i] + 1e-8f) - pos[i];
    #pragma unroll
    for (int off = 1; off < 64; off <<= 1) partial += __shfl_xor(partial, off);
    __shared__ float red[16];
    if ((t & 63) == 0) red[t >> 6] = partial;
    __syncthreads();
    if (t == 0) {
        float s = 0.f;
        #pragma unroll
        for (int i = 0; i < 16; ++i) s += red[i];
        out[0] = s * (1.0f / (float)N2);
    }
}

// ---------------------------------------------------------------------------
extern "C" void kernel_launch(void* const* d_in, const int* in_sizes, int n_in,
                              void* d_out, int out_size, void* d_ws, size_t ws_size,
                              hipStream_t stream) {
    const float* zi = (const float*)d_in[0];
    const float* zj = (const float*)d_in[1];
    char* ws = (char*)d_ws;
    uint2* zn8   = (uint2*)ws;                               // 8192*512 fp8 = 4 MB
    float* denom = (float*)(ws + (size_t)N2 * D_DIM);        // 8192 f32
    float* pos   = denom + N2;                               // 8192 f32
    float* out   = (float*)d_out;

    normalize_kernel<<<N2 / 4, 256, 0, stream>>>(zi, zj, zn8, denom);
    gram_kernel<<<NTRI, 256, 0, stream>>>((const uchar*)zn8, denom, pos);
    loss_kernel<<<1, 1024, 0, stream>>>(denom, pos, out);
}

// Round 16
// 118.455 us; speedup vs baseline: 1.0361x; 1.0361x over previous
//
#include <hip/hip_runtime.h>
#include <hip/hip_bf16.h>
#include <stdint.h>

#define B_ROWS 4096
#define D_DIM  512
#define N2     8192
#define NBLK   64          // 8192 / 128
#define NTRI   (NBLK * (NBLK + 1) / 2)   // 2080 upper-tri blocks (2080 % 8 == 0)
#define BK     128         // fp8: 128x128 panel = 16 KB; 4 K-steps, 4 drains

typedef __attribute__((ext_vector_type(4))) float f32x4;

// ---------------------------------------------------------------------------
// Kernel 1 (R15-validated): wave-per-row normalize + fp8 cast. Zeroes denom.
// ---------------------------------------------------------------------------
__global__ __launch_bounds__(256) void normalize_kernel(const float* __restrict__ zi,
                                                        const float* __restrict__ zj,
                                                        uint2* __restrict__ zn8,
                                                        float* __restrict__ denom) {
    const int t    = threadIdx.x;
    const int lane = t & 63;
    const int row  = blockIdx.x * 4 + (t >> 6);
    if (lane == 0) denom[row] = 0.0f;

    const float* src = (row < B_ROWS) ? (zi + (size_t)row * D_DIM)
                                      : (zj + (size_t)(row - B_ROWS) * D_DIM);
    const float4 a = ((const float4*)src)[lane * 2 + 0];
    const float4 b = ((const float4*)src)[lane * 2 + 1];
    float ss = a.x*a.x + a.y*a.y + a.z*a.z + a.w*a.w
             + b.x*b.x + b.y*b.y + b.z*b.z + b.w*b.w;
    #pragma unroll
    for (int off = 1; off < 64; off <<= 1) ss += __shfl_xor(ss, off);
    const float inv = 1.0f / sqrtf(ss);   // norms ~22.6 >> eps

    int w0 = __builtin_amdgcn_cvt_pk_fp8_f32(a.x * inv, a.y * inv, 0, false);
    w0     = __builtin_amdgcn_cvt_pk_fp8_f32(a.z * inv, a.w * inv, w0, true);
    int w1 = __builtin_amdgcn_cvt_pk_fp8_f32(b.x * inv, b.y * inv, 0, false);
    w1     = __builtin_amdgcn_cvt_pk_fp8_f32(b.z * inv, b.w * inv, w1, true);
    uint2 h; h.x = (unsigned)w0; h.y = (unsigned)w1;
    zn8[(size_t)row * (D_DIM / 8) + lane] = h;
}

// ---------------------------------------------------------------------------
// Kernel 2 (R16): R14's SIMPLE single-buffer loop (dbuf disproven twice),
// BK 64 -> 128: 4 K-steps / 4 barrier-drains per block. LDS 16+16 KB.
// 3-bit XOR chunk swizzle for 128B rows (16-way -> ~2-way):
//   LDS cell (r, c) holds global chunk c ^ (r&7); staging keeps linear
//   gload_lds dest + pre-swizzled source; readers apply same XOR.
// T1 XCD swizzle + tri-decode + fused epilogue unchanged (all validated).
// ---------------------------------------------------------------------------
__global__ __launch_bounds__(256) void gram_kernel(const uchar* __restrict__ zn8,
                                                   float* __restrict__ denom,
                                                   float* __restrict__ pos) {
    __shared__ uchar As[128 * BK];   // 16 KB
    __shared__ uchar Bs[128 * BK];   // 16 KB

    const int t    = threadIdx.x;
    const int lane = t & 63;
    const int wave = t >> 6;
    const int wr   = wave >> 1;       // wave-row quadrant (0..1)
    const int wc   = wave & 1;        // wave-col quadrant (0..1)

    // T1: XCD-chunked bijective swizzle (2080 = 8 * 260), then tri-decode
    const int g   = blockIdx.x;
    const int bid = (g & 7) * (NTRI / 8) + (g >> 3);
    int by = (int)((sqrtf(8.0f * (float)bid + 1.0f) - 1.0f) * 0.5f);
    while ((by * (by + 1)) / 2 > bid) --by;
    while (((by + 1) * (by + 2)) / 2 <= bid) ++by;
    const int bx = bid - (by * (by + 1)) / 2;
    const int row0 = bx * 128;
    const int col0 = by * 128;
    const bool offdiag = (bx != by);

    // staging: per 4KB shot, thread t -> dest row (t>>3)+shot*32, dest chunk
    // t&7 (linear dest = t*16 + shot*4096). SOURCE chunk = (t&7) ^ (row&7)
    // = (t&7) ^ ((t>>3)&7)  (shot*32 == 0 mod 8, so shot-safe).
    const int srow = t >> 3;                                   // 0..31
    const int scol = (((t & 7) ^ ((t >> 3) & 7)) * 16);        // swizzled src bytes

    f32x4 acc[4][4];
    #pragma unroll
    for (int m = 0; m < 4; ++m)
        #pragma unroll
        for (int n = 0; n < 4; ++n)
            acc[m][n] = (f32x4){0.f, 0.f, 0.f, 0.f};

    const int lrow_a = wr * 64 + (lane & 15);
    const int lrow_b = wc * 64 + (lane & 15);
    const int hi     = lane >> 4;            // 0..3
    const int g8     = (lane & 7);           // (row&7) for this lane's rows (row≡lane&15 mod 16)

    for (int kt = 0; kt < D_DIM / BK; ++kt) {
        const int k0 = kt * BK;
        #pragma unroll
        for (int shot = 0; shot < 4; ++shot) {
            const int r = srow + shot * 32;
            const uchar* gA = zn8 + (size_t)(row0 + r) * D_DIM + k0 + scol;
            const uchar* gB = zn8 + (size_t)(col0 + r) * D_DIM + k0 + scol;
            __builtin_amdgcn_global_load_lds(
                (const __attribute__((address_space(1))) void*)gA,
                (__attribute__((address_space(3))) void*)(As + (size_t)(t + shot * 256) * 16),
                16, 0, 0);
            __builtin_amdgcn_global_load_lds(
                (const __attribute__((address_space(1))) void*)gB,
                (__attribute__((address_space(3))) void*)(Bs + (size_t)(t + shot * 256) * 16),
                16, 0, 0);
        }
        __syncthreads();   // compiler emits vmcnt(0)+lgkmcnt(0) drain

        // four K=32 slices per BK=128 step; lane's global chunk (2s + hi>>1)
        // lives in LDS chunk ((2s + (hi>>1)) ^ g8), intra-chunk offset (hi&1)*8
        #pragma unroll
        for (int s = 0; s < 4; ++s) {
            const int ca = (((2 * s + (hi >> 1)) ^ g8) * 16) + (hi & 1) * 8;
            long long af[4], bfr[4];
            #pragma unroll
            for (int m = 0; m < 4; ++m)
                af[m] = *(const long long*)(As + (size_t)(lrow_a + m * 16) * BK + ca);
            #pragma unroll
            for (int n = 0; n < 4; ++n)
                bfr[n] = *(const long long*)(Bs + (size_t)(lrow_b + n * 16) * BK + ca);

            #pragma unroll
            for (int m = 0; m < 4; ++m)
                #pragma unroll
                for (int n = 0; n < 4; ++n)
                    acc[m][n] = __builtin_amdgcn_mfma_f32_16x16x32_fp8_fp8(af[m], bfr[n], acc[m][n], 0, 0, 0);
        }
        __syncthreads();
    }

    // Epilogue: e = exp(2s) (diag masked); positives at gcol-grow==B;
    // row sums into denom[row]; col sums into denom[col] for off-diag blocks.
    const int colbase = col0 + wc * 64 + (lane & 15);
    float cs[4] = {0.f, 0.f, 0.f, 0.f};
    #pragma unroll
    for (int m = 0; m < 4; ++m) {
        const int rowbase = row0 + wr * 64 + m * 16 + (lane >> 4) * 4;
        float rs[4] = {0.f, 0.f, 0.f, 0.f};
        #pragma unroll
        for (int n = 0; n < 4; ++n) {
            const int gcol = colbase + n * 16;
            #pragma unroll
            for (int j = 0; j < 4; ++j) {
                const int grow = rowbase + j;
                const float s2 = 2.0f * acc[m][n][j];   // sim / T,  T = 0.5
                const float e  = (grow == gcol) ? 0.0f : __expf(s2);
                if (gcol - grow == B_ROWS) {            // +B diagonal (once per pair)
                    pos[grow] = s2;
                    pos[gcol] = s2;
                }
                rs[j] += e;
                cs[n] += e;
            }
        }
        #pragma unroll
        for (int off = 1; off < 16; off <<= 1) {
            rs[0] += __shfl_xor(rs[0], off);
            rs[1] += __shfl_xor(rs[1], off);
            rs[2] += __shfl_xor(rs[2], off);
            rs[3] += __shfl_xor(rs[3], off);
        }
        if ((lane & 15) == 0) {
            atomicAdd(&denom[rowbase + 0], rs[0]);
            atomicAdd(&denom[rowbase + 1], rs[1]);
            atomicAdd(&denom[rowbase + 2], rs[2]);
            atomicAdd(&denom[rowbase + 3], rs[3]);
        }
    }
    if (offdiag) {
        #pragma unroll
        for (int off = 16; off < 64; off <<= 1) {
            cs[0] += __shfl_xor(cs[0], off);
            cs[1] += __shfl_xor(cs[1], off);
            cs[2] += __shfl_xor(cs[2], off);
            cs[3] += __shfl_xor(cs[3], off);
        }
        if (lane < 16) {
            atomicAdd(&denom[colbase + 0],  cs[0]);
            atomicAdd(&denom[colbase + 16], cs[1]);
            atomicAdd(&denom[colbase + 32], cs[2]);
            atomicAdd(&denom[colbase + 48], cs[3]);
        }
    }
}

// ---------------------------------------------------------------------------
// Kernel 3: loss = mean( log(denom + 1e-8) - pos )
// ---------------------------------------------------------------------------
__global__ void loss_kernel(const float* __restrict__ denom,
                            const float* __restrict__ pos,
                            float* __restrict__ out) {
    const int t = threadIdx.x;      // 1024 threads
    float partial = 0.f;
    for (int i = t; i < N2; i += 1024)
        partial += logf(denom[i] + 1e-8f) - pos[i];
    #pragma unroll
    for (int off = 1; off < 64; off <<= 1) partial += __shfl_xor(partial, off);
    __shared__ float red[16];
    if ((t & 63) == 0) red[t >> 6] = partial;
    __syncthreads();
    if (t == 0) {
        float s = 0.f;
        #pragma unroll
        for (int i = 0; i < 16; ++i) s += red[i];
        out[0] = s * (1.0f / (float)N2);
    }
}

// ---------------------------------------------------------------------------
extern "C" void kernel_launch(void* const* d_in, const int* in_sizes, int n_in,
                              void* d_out, int out_size, void* d_ws, size_t ws_size,
                              hipStream_t stream) {
    const float* zi = (const float*)d_in[0];
    const float* zj = (const float*)d_in[1];
    char* ws = (char*)d_ws;
    uint2* zn8   = (uint2*)ws;                               // 8192*512 fp8 = 4 MB
    float* denom = (float*)(ws + (size_t)N2 * D_DIM);        // 8192 f32
    float* pos   = denom + N2;                               // 8192 f32
    float* out   = (float*)d_out;

    normalize_kernel<<<N2 / 4, 256, 0, stream>>>(zi, zj, zn8, denom);
    gram_kernel<<<NTRI, 256, 0, stream>>>((const uchar*)zn8, denom, pos);
    loss_kernel<<<1, 1024, 0, stream>>>(denom, pos, out);
}